// Round 4
// baseline (463.292 us; speedup 1.0000x reference)
//
#include <hip/hip_runtime.h>
#include <hip/hip_bf16.h>

// GCN 4-layer, N=50000, E=800000, dims 100->512->256->128->200.
// fp16 MFMA GEMMs with LDS-resident weight tile (no K-loop barriers),
// fp16 gathers with x4-unrolled edge loop, CSR built in ws each call.

#define NN 50000
#define NE 800000

typedef __attribute__((ext_vector_type(8))) _Float16 f16x8;
typedef __attribute__((ext_vector_type(4))) float floatx4;

union U16x8 {
    uint4 u4;
    f16x8 h;
    _Float16 e[8];
};

// ---------------- edge-index dtype detect ----------------
// int64 little-endian with values in [0, 50000) => every odd 32-bit word == 0.
__global__ void detect_kernel(const unsigned* ei, int* flag) {
    __shared__ int nonzero;
    if (threadIdx.x == 0) nonzero = 0;
    __syncthreads();
    unsigned w = ei[2 * threadIdx.x + 1];
    if (w) atomicOr(&nonzero, 1);
    __syncthreads();
    if (threadIdx.x == 0) *flag = nonzero ? 0 : 1;  // 1 => int64
}

__device__ __forceinline__ int load_idx(const void* ei, int isflag64, size_t pos) {
    if (isflag64) return (int)((const long long*)ei)[pos];
    return ((const int*)ei)[pos];
}

__global__ __launch_bounds__(256) void count_kernel(const void* ei,
                                                    const int* __restrict__ flag,
                                                    unsigned* __restrict__ cnt) {
    int e = blockIdx.x * blockDim.x + threadIdx.x;
    if (e >= NE) return;
    int c = load_idx(ei, *flag, (size_t)NE + e);
    atomicAdd(&cnt[c], 1u);
}

__global__ __launch_bounds__(256) void dinv_kernel(const unsigned* __restrict__ cnt,
                                                   float* __restrict__ dinv) {
    int i = blockIdx.x * blockDim.x + threadIdx.x;
    if (i >= NN) return;
    dinv[i] = rsqrtf((float)(cnt[i] + 1u));
}

// hierarchical scan: 49 blocks x 1024 elems
__global__ __launch_bounds__(256) void scan1_kernel(const unsigned* __restrict__ cnt,
                                                    int* __restrict__ off,
                                                    int* __restrict__ bsum) {
    __shared__ int ws[4];
    int b = blockIdx.x, t = threadIdx.x;
    int base = b * 1024 + t * 4;
    int v[4];
    int s = 0;
#pragma unroll
    for (int i = 0; i < 4; i++) {
        int val = (base + i < NN) ? (int)cnt[base + i] : 0;
        v[i] = s;
        s += val;
    }
    int lane = t & 63, wv = t >> 6;
    int x = s;
    for (int d = 1; d < 64; d <<= 1) {
        int y = __shfl_up(x, d, 64);
        if (lane >= d) x += y;
    }
    if (lane == 63) ws[wv] = x;
    __syncthreads();
    int wpre = 0;
#pragma unroll
    for (int i = 0; i < 4; i++)
        if (i < wv) wpre += ws[i];
    int texcl = x - s + wpre;
#pragma unroll
    for (int i = 0; i < 4; i++)
        if (base + i < NN) off[base + i] = texcl + v[i];
    if (t == 255) bsum[b] = texcl + s;
}

__global__ void scan2_kernel(int* bsum, int nb) {
    int t = threadIdx.x;
    int v = (t < nb) ? bsum[t] : 0;
    int x = v;
    for (int d = 1; d < 64; d <<= 1) {
        int y = __shfl_up(x, d, 64);
        if (t >= d) x += y;
    }
    if (t < nb) bsum[t] = x - v;
}

__global__ __launch_bounds__(256) void scan3_kernel(int* __restrict__ off,
                                                    const int* __restrict__ bsum) {
    int b = blockIdx.x;
    int add = bsum[b];
    int base = b * 1024 + threadIdx.x * 4;
#pragma unroll
    for (int i = 0; i < 4; i++)
        if (base + i < NN) off[base + i] += add;
    if (b == 0 && threadIdx.x == 0) off[NN] = NE;
}

// fill CSR: ep[pos] = {src_row, bitcast(norm)}
__global__ __launch_bounds__(256) void fill_kernel(
    const void* ei, const int* __restrict__ flag, const int* __restrict__ off,
    unsigned* __restrict__ fillc, const float* __restrict__ dinv,
    int2* __restrict__ ep) {
    int e = blockIdx.x * blockDim.x + threadIdx.x;
    if (e >= NE) return;
    int f64 = *flag;
    int r = load_idx(ei, f64, e);
    int c = load_idx(ei, f64, (size_t)NE + e);
    int pos = off[c] + (int)atomicAdd(&fillc[c], 1u);
    int2 v;
    v.x = r;
    v.y = __float_as_int(dinv[r] * dinv[c]);
    ep[pos] = v;
}

// x fp32 [NN,100] -> f16 [NN,128] zero-padded
__global__ __launch_bounds__(256) void xcast_kernel(const float* __restrict__ x,
                                                    _Float16* __restrict__ xb) {
    int tid = blockIdx.x * 256 + threadIdx.x;
    int node = tid >> 4, sub = tid & 15;
    if (node >= NN) return;
    int base = sub * 8;
    U16x8 o;
#pragma unroll
    for (int i = 0; i < 8; i++) {
        int c = base + i;
        float v = (c < 100) ? x[(size_t)node * 100 + c] : 0.f;
        o.e[i] = (_Float16)v;
    }
    *(uint4*)(xb + (size_t)node * 128 + base) = o.u4;
}

// all 4 weights: W [K,N] fp32 -> Wt [Npad,Kpad] f16 (transposed, zero-padded)
__global__ __launch_bounds__(256) void wcast_all(
    const float* __restrict__ W1, const float* __restrict__ W2,
    const float* __restrict__ W3, const float* __restrict__ W4,
    _Float16* __restrict__ w1t, _Float16* __restrict__ w2t,
    _Float16* __restrict__ w3t, _Float16* __restrict__ w4t) {
    int b = blockIdx.x, t = threadIdx.x;
    const float* W;
    _Float16* Wt;
    int K, N, Kpad, tid;
    if (b < 256)      { W = W1; Wt = w1t; K = 100; N = 512; Kpad = 128; tid = b * 256 + t; }
    else if (b < 768) { W = W2; Wt = w2t; K = 512; N = 256; Kpad = 512; tid = (b - 256) * 256 + t; }
    else if (b < 896) { W = W3; Wt = w3t; K = 256; N = 128; Kpad = 256; tid = (b - 768) * 256 + t; }
    else              { W = W4; Wt = w4t; K = 128; N = 200; Kpad = 128; tid = (b - 896) * 256 + t; }
    int n = tid / Kpad, k = tid - n * Kpad;
    float v = (k < K && n < N) ? W[(size_t)k * N + n] : 0.f;
    Wt[tid] = (_Float16)v;
}

// aggregation: D/8 lanes per node, f16 in/out, fp32 accumulate.
// Edge loop unrolled x4 for memory-level parallelism.
template <int D, int BR>
__global__ __launch_bounds__(256) void agg_kernel(
    const _Float16* __restrict__ H, const int* __restrict__ off,
    const int2* __restrict__ ep, const float* __restrict__ dinv,
    const float* __restrict__ bias, _Float16* __restrict__ O) {
    constexpr int LPN = D / 8;
    int tid = blockIdx.x * 256 + threadIdx.x;
    int node = tid / LPN;
    int sub = tid % LPN;
    if (node >= NN) return;
    int s = off[node], e = off[node + 1];
    float dc = dinv[node];
    float selfw = dc * dc;
    const int base = sub * 8;
    const _Float16* __restrict__ Hb = H + base;
    float acc[8];
    {
        U16x8 v;
        v.u4 = *(const uint4*)(Hb + (size_t)node * D);
#pragma unroll
        for (int i = 0; i < 8; i++) acc[i] = selfw * (float)v.e[i];
    }
    int j = s;
    int nburst = (e - s) >> 2;
    for (int bb = 0; bb < nburst; bb++, j += 4) {
        int2 q0 = ep[j];
        int2 q1 = ep[j + 1];
        int2 q2 = ep[j + 2];
        int2 q3 = ep[j + 3];
        uint4 a0 = *(const uint4*)(Hb + (size_t)q0.x * D);
        uint4 a1 = *(const uint4*)(Hb + (size_t)q1.x * D);
        uint4 a2 = *(const uint4*)(Hb + (size_t)q2.x * D);
        uint4 a3 = *(const uint4*)(Hb + (size_t)q3.x * D);
        float w0 = __int_as_float(q0.y), w1 = __int_as_float(q1.y);
        float w2 = __int_as_float(q2.y), w3 = __int_as_float(q3.y);
        U16x8 u0, u1, u2, u3;
        u0.u4 = a0; u1.u4 = a1; u2.u4 = a2; u3.u4 = a3;
#pragma unroll
        for (int i = 0; i < 8; i++) acc[i] = fmaf(w0, (float)u0.e[i], acc[i]);
#pragma unroll
        for (int i = 0; i < 8; i++) acc[i] = fmaf(w1, (float)u1.e[i], acc[i]);
#pragma unroll
        for (int i = 0; i < 8; i++) acc[i] = fmaf(w2, (float)u2.e[i], acc[i]);
#pragma unroll
        for (int i = 0; i < 8; i++) acc[i] = fmaf(w3, (float)u3.e[i], acc[i]);
    }
    for (; j < e; j++) {
        int2 q0 = ep[j];
        U16x8 u0;
        u0.u4 = *(const uint4*)(Hb + (size_t)q0.x * D);
        float w0 = __int_as_float(q0.y);
#pragma unroll
        for (int i = 0; i < 8; i++) acc[i] = fmaf(w0, (float)u0.e[i], acc[i]);
    }
    if (BR) {
#pragma unroll
        for (int i = 0; i < 8; i++) acc[i] = fmaxf(acc[i] + bias[base + i], 0.f);
    }
    U16x8 o;
#pragma unroll
    for (int i = 0; i < 8; i++) o.e[i] = (_Float16)acc[i];
    *(uint4*)(O + (size_t)node * D + base) = o.u4;
}

// MFMA GEMM: C[M,N] = A[M,K] @ B^T, B is [Npad,K] f16 (weight, LDS-resident).
// Block = 256 threads = 4 waves; tile 256m x 64n; wave w owns rows [w*64, w*64+64).
// B tile [64,K] loaded to LDS once -> NO barriers in the K-loop; A-fragments
// stream global->register. K-loop stepped 64 (2x32 manual) for 8 in-flight loads.
// EPI: 0 = store f16, 1 = bias+relu store f16, 2 = bias+relu+column-mean atomic.
template <int K, int EPI>
__global__ __launch_bounds__(256) void gemm_kernel(
    const _Float16* __restrict__ A, const _Float16* __restrict__ B,
    const float* __restrict__ bias, _Float16* __restrict__ Cb,
    float* __restrict__ outmean, int M, int N) {
    constexpr int LDK = K + 8;  // +16B pad: row->row bank offset 4, conflict-free-ish
    __shared__ _Float16 Bsl[64 * LDK];
    __shared__ float red[64];
    const int n0 = blockIdx.x * 64;
    const int m0 = blockIdx.y * 256;
    const int t = threadIdx.x;
    const int lane = t & 63, w = t >> 6;
    const int r16 = lane & 15, quad = lane >> 4;

    // stage B tile [64, K] -> LDS (once)
    for (int idx = t; idx < 64 * (K / 8); idx += 256) {
        int row = idx / (K / 8);
        int k8 = (idx - row * (K / 8)) * 8;
        *(uint4*)(Bsl + row * LDK + k8) = *(const uint4*)(B + (size_t)(n0 + row) * K + k8);
    }
    __syncthreads();

    floatx4 acc[4][4];
    const floatx4 fz = {0.f, 0.f, 0.f, 0.f};
#pragma unroll
    for (int i = 0; i < 4; i++)
#pragma unroll
        for (int j = 0; j < 4; j++) acc[i][j] = fz;

    const int mw = m0 + w * 64;
    int gm[4];
#pragma unroll
    for (int i = 0; i < 4; i++) {
        int r = mw + i * 16 + r16;
        gm[i] = (r > M - 1) ? (M - 1) : r;
    }

#pragma unroll 1
    for (int kc = 0; kc < K; kc += 64) {
        f16x8 af0[4], bf0[4], af1[4], bf1[4];
#pragma unroll
        for (int i = 0; i < 4; i++)
            af0[i] = *(const f16x8*)(A + (size_t)gm[i] * K + kc + quad * 8);
#pragma unroll
        for (int i = 0; i < 4; i++)
            af1[i] = *(const f16x8*)(A + (size_t)gm[i] * K + kc + 32 + quad * 8);
#pragma unroll
        for (int j = 0; j < 4; j++)
            bf0[j] = *(const f16x8*)(Bsl + (j * 16 + r16) * LDK + kc + quad * 8);
#pragma unroll
        for (int j = 0; j < 4; j++)
            bf1[j] = *(const f16x8*)(Bsl + (j * 16 + r16) * LDK + kc + 32 + quad * 8);
#pragma unroll
        for (int i = 0; i < 4; i++)
#pragma unroll
            for (int j = 0; j < 4; j++)
                acc[i][j] = __builtin_amdgcn_mfma_f32_16x16x32_f16(af0[i], bf0[j], acc[i][j], 0, 0, 0);
#pragma unroll
        for (int i = 0; i < 4; i++)
#pragma unroll
            for (int j = 0; j < 4; j++)
                acc[i][j] = __builtin_amdgcn_mfma_f32_16x16x32_f16(af1[i], bf1[j], acc[i][j], 0, 0, 0);
    }

    if (EPI == 2) {
        if (t < 64) red[t] = 0.f;
        __syncthreads();
#pragma unroll
        for (int j = 0; j < 4; j++) {
            int col = n0 + j * 16 + r16;
            float s = 0.f;
            if (col < N) {
                float bv = bias[col];
#pragma unroll
                for (int i = 0; i < 4; i++) {
                    int mbase = mw + i * 16 + quad * 4;
#pragma unroll
                    for (int r = 0; r < 4; r++)
                        if (mbase + r < M) s += fmaxf(acc[i][j][r] + bv, 0.f);
                }
            }
            atomicAdd(&red[j * 16 + r16], s);
        }
        __syncthreads();
        if (t < 64) {
            int col = n0 + t;
            if (col < N) atomicAdd(outmean + col, red[t] * (1.0f / (float)NN));
        }
    } else {
#pragma unroll
        for (int i = 0; i < 4; i++) {
            int mbase = mw + i * 16 + quad * 4;
#pragma unroll
            for (int r = 0; r < 4; r++) {
                int m = mbase + r;
                if (m >= M) continue;
#pragma unroll
                for (int j = 0; j < 4; j++) {
                    int col = n0 + j * 16 + r16;
                    float v = acc[i][j][r];
                    if (EPI == 1) v = fmaxf(v + bias[col], 0.f);
                    Cb[(size_t)m * N + col] = (_Float16)v;
                }
            }
        }
    }
}

extern "C" void kernel_launch(void* const* d_in, const int* in_sizes, int n_in,
                              void* d_out, int out_size, void* d_ws, size_t ws_size,
                              hipStream_t stream) {
    const float* x  = (const float*)d_in[0];
    const void*  ei = d_in[1];
    const float* W1 = (const float*)d_in[2];
    const float* b1 = (const float*)d_in[3];
    const float* W2 = (const float*)d_in[4];
    const float* b2 = (const float*)d_in[5];
    const float* W3 = (const float*)d_in[6];
    const float* b3 = (const float*)d_in[7];
    const float* W4 = (const float*)d_in[8];
    const float* b4 = (const float*)d_in[9];
    float* out = (float*)d_out;

    char* ws = (char*)d_ws;
    size_t o = 0;
    auto alloc = [&](size_t bytes) -> void* {
        void* p = ws + o;
        o += (bytes + 255) & ~(size_t)255;
        return p;
    };
    int*      flag  = (int*)alloc(4);
    unsigned* cnt   = (unsigned*)alloc((size_t)NN * 4);
    int*      off   = (int*)alloc((size_t)(NN + 1) * 4);
    unsigned* fillc = (unsigned*)alloc((size_t)NN * 4);
    float*    dinv  = (float*)alloc((size_t)NN * 4);
    int2*     ep    = (int2*)alloc((size_t)NE * 8);
    int*      bsum  = (int*)alloc(256);
    _Float16* w1t = (_Float16*)alloc((size_t)512 * 128 * 2);
    _Float16* w2t = (_Float16*)alloc((size_t)256 * 512 * 2);
    _Float16* w3t = (_Float16*)alloc((size_t)128 * 256 * 2);
    _Float16* w4t = (_Float16*)alloc((size_t)256 * 128 * 2);
    // arenas with lifetime overlays
    _Float16* arena1 = (_Float16*)alloc((size_t)NN * 512 * 2);  // 51.2 MB
    _Float16* arena2 = (_Float16*)alloc((size_t)NN * 256 * 2);  // 25.6 MB
    _Float16* arena3 = (_Float16*)alloc((size_t)NN * 256 * 2);  // 25.6 MB
    _Float16* xb  = arena1;  // [NN,128], dead after agg1
    _Float16* A1b = arena2;  // [NN,128], dead after gemm1
    _Float16* H1b = arena1;  // [NN,512], dead after gemm2
    _Float16* t2b = arena2;  // [NN,256], dead after agg2
    _Float16* H2b = arena3;  // [NN,256], dead after gemm3
    _Float16* t3b = arena1;  // [NN,128], dead after agg3
    _Float16* h3b = arena2;  // [NN,128], dead after agg4
    _Float16* A4b = arena1;  // [NN,128], dead after gemm4

    hipMemsetAsync(cnt, 0, (size_t)NN * 4, stream);
    hipMemsetAsync(fillc, 0, (size_t)NN * 4, stream);
    hipMemsetAsync(out, 0, 200 * 4, stream);

    const int EB = (NE + 255) / 256;     // 3125
    const int NB1 = (NN + 1023) / 1024;  // 49

    detect_kernel<<<1, 256, 0, stream>>>((const unsigned*)ei, flag);
    count_kernel<<<EB, 256, 0, stream>>>(ei, flag, cnt);
    dinv_kernel<<<(NN + 255) / 256, 256, 0, stream>>>(cnt, dinv);
    scan1_kernel<<<NB1, 256, 0, stream>>>(cnt, off, bsum);
    scan2_kernel<<<1, 64, 0, stream>>>(bsum, NB1);
    scan3_kernel<<<NB1, 256, 0, stream>>>(off, bsum);
    fill_kernel<<<EB, 256, 0, stream>>>(ei, flag, off, fillc, dinv, ep);

    xcast_kernel<<<(NN * 16 + 255) / 256, 256, 0, stream>>>(x, xb);
    wcast_all<<<1024, 256, 0, stream>>>(W1, W2, W3, W4, w1t, w2t, w3t, w4t);

    const int MB = (NN + 255) / 256;  // 196 m-blocks

    // L1: agg(x) -> A1; gemm + bias + relu -> H1 [NN,512]
    agg_kernel<128, 0><<<(NN * 16 + 255) / 256, 256, 0, stream>>>(xb, off, ep, dinv, nullptr, A1b);
    gemm_kernel<128, 1><<<dim3(8, MB), 256, 0, stream>>>(A1b, w1t, b1, H1b, nullptr, NN, 512);
    // L2: gemm H1 -> t2 [NN,256]; agg + bias + relu -> H2
    gemm_kernel<512, 0><<<dim3(4, MB), 256, 0, stream>>>(H1b, w2t, nullptr, t2b, nullptr, NN, 256);
    agg_kernel<256, 1><<<(NN * 32 + 255) / 256, 256, 0, stream>>>(t2b, off, ep, dinv, b2, H2b);
    // L3: gemm H2 -> t3 [NN,128]; agg + bias + relu -> h3
    gemm_kernel<256, 0><<<dim3(2, MB), 256, 0, stream>>>(H2b, w3t, nullptr, t3b, nullptr, NN, 128);
    agg_kernel<128, 1><<<(NN * 16 + 255) / 256, 256, 0, stream>>>(t3b, off, ep, dinv, b3, h3b);
    // L4: agg(h3) -> A4; gemm + bias + relu + fused column mean -> out
    agg_kernel<128, 0><<<(NN * 16 + 255) / 256, 256, 0, stream>>>(h3b, off, ep, dinv, nullptr, A4b);
    gemm_kernel<128, 2><<<dim3(4, MB), 256, 0, stream>>>(A4b, w4t, b4, nullptr, out, NN, 200);
}

// Round 5
// 430.879 us; speedup vs baseline: 1.0752x; 1.0752x over previous
//
#include <hip/hip_runtime.h>
#include <hip/hip_bf16.h>

// GCN 4-layer, N=50000, E=800000, dims 100->512->256->128->200.
// fp16 MFMA GEMMs (128x128 tile), fp16 gathers (x2 unroll), CSR in ws.
// Setup chain fused: 15 graph nodes total (was 22).

#define NN 50000
#define NE 800000

typedef __attribute__((ext_vector_type(8))) _Float16 f16x8;
typedef __attribute__((ext_vector_type(4))) float floatx4;

union U16x8 {
    uint4 u4;
    f16x8 h;
    _Float16 e[8];
};

// ---------------- fused zero + dtype-detect ----------------
// zeroes cnt/fillc/out; block 0 detects int64 vs int32 edge_index.
__global__ __launch_bounds__(256) void zero_detect_kernel(
    const unsigned* __restrict__ ei, int* __restrict__ flag,
    unsigned* __restrict__ cnt, unsigned* __restrict__ fillc,
    float* __restrict__ out) {
    int tid = blockIdx.x * 256 + threadIdx.x;
    if (tid < NN) {
        cnt[tid] = 0u;
        fillc[tid] = 0u;
    }
    if (blockIdx.x == 0) {
        if (threadIdx.x < 200) out[threadIdx.x] = 0.f;
        // int64 little-endian values < 2^31 => every odd 32-bit word == 0
        unsigned w = ei[2 * threadIdx.x + 1];
        unsigned long long any = __ballot(w != 0);
        if (threadIdx.x == 0) *flag = (any == 0ull) ? 1 : 0;
    }
}

__device__ __forceinline__ int load_idx(const void* ei, int isflag64, size_t pos) {
    if (isflag64) return (int)((const long long*)ei)[pos];
    return ((const int*)ei)[pos];
}

__global__ __launch_bounds__(256) void count_kernel(const void* ei,
                                                    const int* __restrict__ flag,
                                                    unsigned* __restrict__ cnt) {
    int e = blockIdx.x * blockDim.x + threadIdx.x;
    if (e >= NE) return;
    int c = load_idx(ei, *flag, (size_t)NE + e);
    atomicAdd(&cnt[c], 1u);
}

// hierarchical scan step 1 (49 blocks x 1024 elems) + fused dinv
__global__ __launch_bounds__(256) void scan1_kernel(const unsigned* __restrict__ cnt,
                                                    int* __restrict__ off,
                                                    int* __restrict__ bsum,
                                                    float* __restrict__ dinv) {
    __shared__ int ws[4];
    int b = blockIdx.x, t = threadIdx.x;
    int base = b * 1024 + t * 4;
    int v[4];
    int s = 0;
#pragma unroll
    for (int i = 0; i < 4; i++) {
        int val = 0;
        if (base + i < NN) {
            val = (int)cnt[base + i];
            dinv[base + i] = rsqrtf((float)(val + 1));
        }
        v[i] = s;
        s += val;
    }
    int lane = t & 63, wv = t >> 6;
    int x = s;
    for (int d = 1; d < 64; d <<= 1) {
        int y = __shfl_up(x, d, 64);
        if (lane >= d) x += y;
    }
    if (lane == 63) ws[wv] = x;
    __syncthreads();
    int wpre = 0;
#pragma unroll
    for (int i = 0; i < 4; i++)
        if (i < wv) wpre += ws[i];
    int texcl = x - s + wpre;
#pragma unroll
    for (int i = 0; i < 4; i++)
        if (base + i < NN) off[base + i] = texcl + v[i];
    if (t == 255) bsum[b] = texcl + s;
}

__global__ void scan2_kernel(int* bsum, int nb) {
    int t = threadIdx.x;
    int v = (t < nb) ? bsum[t] : 0;
    int x = v;
    for (int d = 1; d < 64; d <<= 1) {
        int y = __shfl_up(x, d, 64);
        if (t >= d) x += y;
    }
    if (t < nb) bsum[t] = x - v;
}

__global__ __launch_bounds__(256) void scan3_kernel(int* __restrict__ off,
                                                    const int* __restrict__ bsum) {
    int b = blockIdx.x;
    int add = bsum[b];
    int base = b * 1024 + threadIdx.x * 4;
#pragma unroll
    for (int i = 0; i < 4; i++)
        if (base + i < NN) off[base + i] += add;
    if (b == 0 && threadIdx.x == 0) off[NN] = NE;
}

// fill CSR: ep[pos] = {src_row, bitcast(norm)}
__global__ __launch_bounds__(256) void fill_kernel(
    const void* ei, const int* __restrict__ flag, const int* __restrict__ off,
    unsigned* __restrict__ fillc, const float* __restrict__ dinv,
    int2* __restrict__ ep) {
    int e = blockIdx.x * blockDim.x + threadIdx.x;
    if (e >= NE) return;
    int f64 = *flag;
    int r = load_idx(ei, f64, e);
    int c = load_idx(ei, f64, (size_t)NE + e);
    int pos = off[c] + (int)atomicAdd(&fillc[c], 1u);
    int2 v;
    v.x = r;
    v.y = __float_as_int(dinv[r] * dinv[c]);
    ep[pos] = v;
}

// fused: x fp32 [NN,100] -> f16 [NN,128] zero-padded (blocks 0..3124)
//      + all 4 weights W [K,N] fp32 -> Wt [Npad,Kpad] f16 (blocks 3125..4148)
__global__ __launch_bounds__(256) void xwcast_kernel(
    const float* __restrict__ x, _Float16* __restrict__ xb,
    const float* __restrict__ W1, const float* __restrict__ W2,
    const float* __restrict__ W3, const float* __restrict__ W4,
    _Float16* __restrict__ w1t, _Float16* __restrict__ w2t,
    _Float16* __restrict__ w3t, _Float16* __restrict__ w4t) {
    int bx = blockIdx.x, t = threadIdx.x;
    if (bx < 3125) {
        int tid = bx * 256 + t;
        int node = tid >> 4, sub = tid & 15;
        if (node >= NN) return;
        int base = sub * 8;
        U16x8 o;
#pragma unroll
        for (int i = 0; i < 8; i++) {
            int c = base + i;
            float v = (c < 100) ? x[(size_t)node * 100 + c] : 0.f;
            o.e[i] = (_Float16)v;
        }
        *(uint4*)(xb + (size_t)node * 128 + base) = o.u4;
        return;
    }
    int b = bx - 3125;
    const float* W;
    _Float16* Wt;
    int K, N, Kpad, tid;
    if (b < 256)      { W = W1; Wt = w1t; K = 100; N = 512; Kpad = 128; tid = b * 256 + t; }
    else if (b < 768) { W = W2; Wt = w2t; K = 512; N = 256; Kpad = 512; tid = (b - 256) * 256 + t; }
    else if (b < 896) { W = W3; Wt = w3t; K = 256; N = 128; Kpad = 256; tid = (b - 768) * 256 + t; }
    else              { W = W4; Wt = w4t; K = 128; N = 200; Kpad = 128; tid = (b - 896) * 256 + t; }
    int n = tid / Kpad, k = tid - n * Kpad;
    float v = (k < K && n < N) ? W[(size_t)k * N + n] : 0.f;
    Wt[tid] = (_Float16)v;
}

// aggregation: D/8 lanes per node, f16 in/out, fp32 accumulate, x2 unroll.
template <int D, int BR>
__global__ __launch_bounds__(256) void agg_kernel(
    const _Float16* __restrict__ H, const int* __restrict__ off,
    const int2* __restrict__ ep, const float* __restrict__ dinv,
    const float* __restrict__ bias, _Float16* __restrict__ O) {
    constexpr int LPN = D / 8;
    int tid = blockIdx.x * 256 + threadIdx.x;
    int node = tid / LPN;
    int sub = tid % LPN;
    if (node >= NN) return;
    int s = off[node], e = off[node + 1];
    float dc = dinv[node];
    float selfw = dc * dc;
    const int base = sub * 8;
    const _Float16* __restrict__ Hb = H + base;
    float acc[8];
    {
        U16x8 v;
        v.u4 = *(const uint4*)(Hb + (size_t)node * D);
#pragma unroll
        for (int i = 0; i < 8; i++) acc[i] = selfw * (float)v.e[i];
    }
    int j = s;
    for (; j + 2 <= e; j += 2) {
        int2 q0 = ep[j];
        int2 q1 = ep[j + 1];
        U16x8 u0, u1;
        u0.u4 = *(const uint4*)(Hb + (size_t)q0.x * D);
        u1.u4 = *(const uint4*)(Hb + (size_t)q1.x * D);
        float w0 = __int_as_float(q0.y);
        float w1 = __int_as_float(q1.y);
#pragma unroll
        for (int i = 0; i < 8; i++) acc[i] = fmaf(w0, (float)u0.e[i], acc[i]);
#pragma unroll
        for (int i = 0; i < 8; i++) acc[i] = fmaf(w1, (float)u1.e[i], acc[i]);
    }
    if (j < e) {
        int2 q0 = ep[j];
        U16x8 u0;
        u0.u4 = *(const uint4*)(Hb + (size_t)q0.x * D);
        float w0 = __int_as_float(q0.y);
#pragma unroll
        for (int i = 0; i < 8; i++) acc[i] = fmaf(w0, (float)u0.e[i], acc[i]);
    }
    if (BR) {
#pragma unroll
        for (int i = 0; i < 8; i++) acc[i] = fmaxf(acc[i] + bias[base + i], 0.f);
    }
    U16x8 o;
#pragma unroll
    for (int i = 0; i < 8; i++) o.e[i] = (_Float16)acc[i];
    *(uint4*)(O + (size_t)node * D + base) = o.u4;
}

// MFMA GEMM: C[M,N] = A[M,K] @ B^T, B is [Npad,K] f16.
// 128x128 tile, 256 threads (2x2 waves of 64x64), 16x16x32 f16 MFMA.
// LDS row stride 40 elems (80 B) to break 8-way bank aliasing.
// EPI: 0 = store f16, 1 = bias+relu store f16, 2 = bias+relu+column-mean atomic.
template <int EPI>
__global__ __launch_bounds__(256) void gemm_kernel(
    const _Float16* __restrict__ A, const _Float16* __restrict__ B,
    const float* __restrict__ bias, _Float16* __restrict__ Cb,
    float* __restrict__ outmean, int M, int K, int N) {
    __shared__ _Float16 Asl[128 * 40];
    __shared__ _Float16 Bsl[128 * 40];
    __shared__ float red[128];
    const int m0 = blockIdx.y * 128;
    const int n0 = blockIdx.x * 128;
    const int t = threadIdx.x;
    const int lane = t & 63, w = t >> 6;
    const int wm = (w >> 1) * 64, wn = (w & 1) * 64;
    const int r16 = lane & 15, quad = lane >> 4;

    floatx4 acc[4][4];
    const floatx4 fz = {0.f, 0.f, 0.f, 0.f};
#pragma unroll
    for (int i = 0; i < 4; i++)
#pragma unroll
        for (int j = 0; j < 4; j++) acc[i][j] = fz;

    for (int kc = 0; kc < K; kc += 32) {
        __syncthreads();
#pragma unroll
        for (int i = 0; i < 2; i++) {
            int seg = t + 256 * i;
            int row = seg >> 2, k8 = (seg & 3) * 8;
            int gm = m0 + row;
            if (gm > M - 1) gm = M - 1;
            *(uint4*)(Asl + row * 40 + k8) = *(const uint4*)(A + (size_t)gm * K + kc + k8);
            int gn = n0 + row;  // B padded to Npad multiple of 128
            *(uint4*)(Bsl + row * 40 + k8) = *(const uint4*)(B + (size_t)gn * K + kc + k8);
        }
        __syncthreads();
        f16x8 af[4], bf[4];
#pragma unroll
        for (int i = 0; i < 4; i++)
            af[i] = *(const f16x8*)(Asl + (wm + i * 16 + r16) * 40 + quad * 8);
#pragma unroll
        for (int j = 0; j < 4; j++)
            bf[j] = *(const f16x8*)(Bsl + (wn + j * 16 + r16) * 40 + quad * 8);
#pragma unroll
        for (int i = 0; i < 4; i++)
#pragma unroll
            for (int j = 0; j < 4; j++)
                acc[i][j] = __builtin_amdgcn_mfma_f32_16x16x32_f16(af[i], bf[j], acc[i][j], 0, 0, 0);
    }

    if (EPI == 2) {
        if (t < 128) red[t] = 0.f;
        __syncthreads();
#pragma unroll
        for (int j = 0; j < 4; j++) {
            int col = n0 + wn + j * 16 + r16;
            float s = 0.f;
            if (col < N) {
                float bv = bias[col];
#pragma unroll
                for (int i = 0; i < 4; i++)
#pragma unroll
                    for (int r = 0; r < 4; r++) {
                        int m = m0 + wm + i * 16 + quad * 4 + r;
                        if (m < M) s += fmaxf(acc[i][j][r] + bv, 0.f);
                    }
            }
            atomicAdd(&red[wn + j * 16 + r16], s);
        }
        __syncthreads();
        if (t < 128) {
            int col = n0 + t;
            if (col < N) atomicAdd(outmean + col, red[t] * (1.0f / (float)NN));
        }
    } else {
#pragma unroll
        for (int i = 0; i < 4; i++)
#pragma unroll
            for (int r = 0; r < 4; r++) {
                int m = m0 + wm + i * 16 + quad * 4 + r;
                if (m >= M) continue;
#pragma unroll
                for (int j = 0; j < 4; j++) {
                    int col = n0 + wn + j * 16 + r16;
                    float v = acc[i][j][r];
                    if (EPI == 1) v = fmaxf(v + bias[col], 0.f);
                    Cb[(size_t)m * N + col] = (_Float16)v;
                }
            }
    }
}

extern "C" void kernel_launch(void* const* d_in, const int* in_sizes, int n_in,
                              void* d_out, int out_size, void* d_ws, size_t ws_size,
                              hipStream_t stream) {
    const float* x  = (const float*)d_in[0];
    const void*  ei = d_in[1];
    const float* W1 = (const float*)d_in[2];
    const float* b1 = (const float*)d_in[3];
    const float* W2 = (const float*)d_in[4];
    const float* b2 = (const float*)d_in[5];
    const float* W3 = (const float*)d_in[6];
    const float* b3 = (const float*)d_in[7];
    const float* W4 = (const float*)d_in[8];
    const float* b4 = (const float*)d_in[9];
    float* out = (float*)d_out;

    char* ws = (char*)d_ws;
    size_t o = 0;
    auto alloc = [&](size_t bytes) -> void* {
        void* p = ws + o;
        o += (bytes + 255) & ~(size_t)255;
        return p;
    };
    int*      flag  = (int*)alloc(4);
    unsigned* cnt   = (unsigned*)alloc((size_t)NN * 4);
    int*      off   = (int*)alloc((size_t)(NN + 1) * 4);
    unsigned* fillc = (unsigned*)alloc((size_t)NN * 4);
    float*    dinv  = (float*)alloc((size_t)NN * 4);
    int2*     ep    = (int2*)alloc((size_t)NE * 8);
    int*      bsum  = (int*)alloc(256);
    _Float16* w1t = (_Float16*)alloc((size_t)512 * 128 * 2);
    _Float16* w2t = (_Float16*)alloc((size_t)256 * 512 * 2);
    _Float16* w3t = (_Float16*)alloc((size_t)128 * 256 * 2);
    _Float16* w4t = (_Float16*)alloc((size_t)256 * 128 * 2);
    // arenas with lifetime overlays
    _Float16* arena1 = (_Float16*)alloc((size_t)NN * 512 * 2);  // 51.2 MB
    _Float16* arena2 = (_Float16*)alloc((size_t)NN * 256 * 2);  // 25.6 MB
    _Float16* arena3 = (_Float16*)alloc((size_t)NN * 256 * 2);  // 25.6 MB
    _Float16* xb  = arena1;  // [NN,128], dead after agg1
    _Float16* A1b = arena2;  // [NN,128], dead after gemm1
    _Float16* H1b = arena1;  // [NN,512], dead after gemm2
    _Float16* t2b = arena2;  // [NN,256], dead after agg2
    _Float16* H2b = arena3;  // [NN,256], dead after gemm3
    _Float16* t3b = arena1;  // [NN,128], dead after agg3
    _Float16* h3b = arena2;  // [NN,128], dead after agg4
    _Float16* A4b = arena1;  // [NN,128], dead after gemm4

    const int EB = (NE + 255) / 256;     // 3125
    const int NB1 = (NN + 1023) / 1024;  // 49
    const int ZB = (NN + 255) / 256;     // 196

    zero_detect_kernel<<<ZB, 256, 0, stream>>>((const unsigned*)ei, flag, cnt, fillc, out);
    count_kernel<<<EB, 256, 0, stream>>>(ei, flag, cnt);
    scan1_kernel<<<NB1, 256, 0, stream>>>(cnt, off, bsum, dinv);
    scan2_kernel<<<1, 64, 0, stream>>>(bsum, NB1);
    scan3_kernel<<<NB1, 256, 0, stream>>>(off, bsum);
    fill_kernel<<<EB, 256, 0, stream>>>(ei, flag, off, fillc, dinv, ep);
    xwcast_kernel<<<3125 + 1024, 256, 0, stream>>>(x, xb, W1, W2, W3, W4, w1t, w2t, w3t, w4t);

    const int MB = (NN + 127) / 128;  // 391

    // L1: agg(x) -> A1; gemm + bias + relu -> H1 [NN,512]
    agg_kernel<128, 0><<<(NN * 16 + 255) / 256, 256, 0, stream>>>(xb, off, ep, dinv, nullptr, A1b);
    gemm_kernel<1><<<dim3(4, MB), 256, 0, stream>>>(A1b, w1t, b1, H1b, nullptr, NN, 128, 512);
    // L2: gemm H1 -> t2 [NN,256]; agg + bias + relu -> H2
    gemm_kernel<0><<<dim3(2, MB), 256, 0, stream>>>(H1b, w2t, nullptr, t2b, nullptr, NN, 512, 256);
    agg_kernel<256, 1><<<(NN * 32 + 255) / 256, 256, 0, stream>>>(t2b, off, ep, dinv, b2, H2b);
    // L3: gemm H2 -> t3 [NN,128]; agg + bias + relu -> h3
    gemm_kernel<0><<<dim3(1, MB), 256, 0, stream>>>(H2b, w3t, nullptr, t3b, nullptr, NN, 256, 128);
    agg_kernel<128, 1><<<(NN * 16 + 255) / 256, 256, 0, stream>>>(t3b, off, ep, dinv, b3, h3b);
    // L4: agg(h3) -> A4; gemm + bias + relu + fused column mean -> out
    agg_kernel<128, 0><<<(NN * 16 + 255) / 256, 256, 0, stream>>>(h3b, off, ep, dinv, nullptr, A4b);
    gemm_kernel<2><<<dim3(2, MB), 256, 0, stream>>>(A4b, w4t, b4, nullptr, out, NN, 128, 200);
}

// Round 6
// 356.040 us; speedup vs baseline: 1.3012x; 1.2102x over previous
//
#include <hip/hip_runtime.h>
#include <hip/hip_bf16.h>

// GCN 4-layer, N=50000, E=800000, dims 100->512->256->128->200.
// fp16 MFMA GEMMs (128x128 tile). Gathered activation tensors stored as
// OCP fp8 e4m3 (halves L2-miss gather traffic); GEMM operands stay fp16,
// weights fp16 (no systematic weight error). CSR built in ws each call.

#define NN 50000
#define NE 800000

typedef __attribute__((ext_vector_type(8))) _Float16 f16x8;
typedef __attribute__((ext_vector_type(4))) float floatx4;
typedef __attribute__((ext_vector_type(2))) float floatx2;

union U16x8 {
    uint4 u4;
    f16x8 h;
    _Float16 e[8];
};

// decode 16 fp8 (16 B) -> 16 fp32 via HW cvt
__device__ __forceinline__ void dec16(const unsigned char* p, float* f) {
    uint4 v = *(const uint4*)p;
    unsigned w[4] = {v.x, v.y, v.z, v.w};
#pragma unroll
    for (int k = 0; k < 4; k++) {
        floatx2 lo = __builtin_amdgcn_cvt_pk_f32_fp8(w[k], false);
        floatx2 hi = __builtin_amdgcn_cvt_pk_f32_fp8(w[k], true);
        f[k * 4 + 0] = lo[0];
        f[k * 4 + 1] = lo[1];
        f[k * 4 + 2] = hi[0];
        f[k * 4 + 3] = hi[1];
    }
}

// encode 16 fp32 -> 16 fp8 (16 B)
__device__ __forceinline__ uint4 enc16(const float* f) {
    uint4 r;
    unsigned w;
    w = __builtin_amdgcn_cvt_pk_fp8_f32(f[0], f[1], 0, false);
    w = __builtin_amdgcn_cvt_pk_fp8_f32(f[2], f[3], (int)w, true);
    r.x = w;
    w = __builtin_amdgcn_cvt_pk_fp8_f32(f[4], f[5], 0, false);
    w = __builtin_amdgcn_cvt_pk_fp8_f32(f[6], f[7], (int)w, true);
    r.y = w;
    w = __builtin_amdgcn_cvt_pk_fp8_f32(f[8], f[9], 0, false);
    w = __builtin_amdgcn_cvt_pk_fp8_f32(f[10], f[11], (int)w, true);
    r.z = w;
    w = __builtin_amdgcn_cvt_pk_fp8_f32(f[12], f[13], 0, false);
    w = __builtin_amdgcn_cvt_pk_fp8_f32(f[14], f[15], (int)w, true);
    r.w = w;
    return r;
}

// ---------------- fused zero + dtype-detect ----------------
__global__ __launch_bounds__(256) void zero_detect_kernel(
    const unsigned* __restrict__ ei, int* __restrict__ flag,
    unsigned* __restrict__ cnt, unsigned* __restrict__ fillc,
    float* __restrict__ out) {
    int tid = blockIdx.x * 256 + threadIdx.x;
    if (tid < NN) {
        cnt[tid] = 0u;
        fillc[tid] = 0u;
    }
    if (blockIdx.x == 0) {
        if (threadIdx.x < 200) out[threadIdx.x] = 0.f;
        // int64 little-endian values < 2^31 => every odd 32-bit word == 0
        unsigned w = ei[2 * threadIdx.x + 1];
        unsigned long long any = __ballot(w != 0);
        if (threadIdx.x == 0) *flag = (any == 0ull) ? 1 : 0;
    }
}

__device__ __forceinline__ int load_idx(const void* ei, int isflag64, size_t pos) {
    if (isflag64) return (int)((const long long*)ei)[pos];
    return ((const int*)ei)[pos];
}

__global__ __launch_bounds__(256) void count_kernel(const void* ei,
                                                    const int* __restrict__ flag,
                                                    unsigned* __restrict__ cnt) {
    int e = blockIdx.x * blockDim.x + threadIdx.x;
    if (e >= NE) return;
    int c = load_idx(ei, *flag, (size_t)NE + e);
    atomicAdd(&cnt[c], 1u);
}

// hierarchical scan step 1 (49 blocks x 1024 elems) + fused dinv
__global__ __launch_bounds__(256) void scan1_kernel(const unsigned* __restrict__ cnt,
                                                    int* __restrict__ off,
                                                    int* __restrict__ bsum,
                                                    float* __restrict__ dinv) {
    __shared__ int ws[4];
    int b = blockIdx.x, t = threadIdx.x;
    int base = b * 1024 + t * 4;
    int v[4];
    int s = 0;
#pragma unroll
    for (int i = 0; i < 4; i++) {
        int val = 0;
        if (base + i < NN) {
            val = (int)cnt[base + i];
            dinv[base + i] = rsqrtf((float)(val + 1));
        }
        v[i] = s;
        s += val;
    }
    int lane = t & 63, wv = t >> 6;
    int x = s;
    for (int d = 1; d < 64; d <<= 1) {
        int y = __shfl_up(x, d, 64);
        if (lane >= d) x += y;
    }
    if (lane == 63) ws[wv] = x;
    __syncthreads();
    int wpre = 0;
#pragma unroll
    for (int i = 0; i < 4; i++)
        if (i < wv) wpre += ws[i];
    int texcl = x - s + wpre;
#pragma unroll
    for (int i = 0; i < 4; i++)
        if (base + i < NN) off[base + i] = texcl + v[i];
    if (t == 255) bsum[b] = texcl + s;
}

__global__ void scan2_kernel(int* bsum, int nb) {
    int t = threadIdx.x;
    int v = (t < nb) ? bsum[t] : 0;
    int x = v;
    for (int d = 1; d < 64; d <<= 1) {
        int y = __shfl_up(x, d, 64);
        if (t >= d) x += y;
    }
    if (t < nb) bsum[t] = x - v;
}

__global__ __launch_bounds__(256) void scan3_kernel(int* __restrict__ off,
                                                    const int* __restrict__ bsum) {
    int b = blockIdx.x;
    int add = bsum[b];
    int base = b * 1024 + threadIdx.x * 4;
#pragma unroll
    for (int i = 0; i < 4; i++)
        if (base + i < NN) off[base + i] += add;
    if (b == 0 && threadIdx.x == 0) off[NN] = NE;
}

// fill CSR: ep[pos] = {src_row, bitcast(norm)}
__global__ __launch_bounds__(256) void fill_kernel(
    const void* ei, const int* __restrict__ flag, const int* __restrict__ off,
    unsigned* __restrict__ fillc, const float* __restrict__ dinv,
    int2* __restrict__ ep) {
    int e = blockIdx.x * blockDim.x + threadIdx.x;
    if (e >= NE) return;
    int f64 = *flag;
    int r = load_idx(ei, f64, e);
    int c = load_idx(ei, f64, (size_t)NE + e);
    int pos = off[c] + (int)atomicAdd(&fillc[c], 1u);
    int2 v;
    v.x = r;
    v.y = __float_as_int(dinv[r] * dinv[c]);
    ep[pos] = v;
}

// fused: x fp32 [NN,100] -> fp8 [NN,128] zero-padded (blocks 0..1562)
//      + all 4 weights W [K,N] fp32 -> Wt [Npad,Kpad] f16 (blocks 1563..2586)
__global__ __launch_bounds__(256) void xwcast_kernel(
    const float* __restrict__ x, unsigned char* __restrict__ xb,
    const float* __restrict__ W1, const float* __restrict__ W2,
    const float* __restrict__ W3, const float* __restrict__ W4,
    _Float16* __restrict__ w1t, _Float16* __restrict__ w2t,
    _Float16* __restrict__ w3t, _Float16* __restrict__ w4t) {
    int bx = blockIdx.x, t = threadIdx.x;
    if (bx < 1563) {
        int tid = bx * 256 + t;
        int node = tid >> 3, sub = tid & 7;
        if (node >= NN) return;
        int base = sub * 16;
        float f[16];
#pragma unroll
        for (int i = 0; i < 16; i++) {
            int c = base + i;
            f[i] = (c < 100) ? x[(size_t)node * 100 + c] : 0.f;
        }
        *(uint4*)(xb + (size_t)node * 128 + base) = enc16(f);
        return;
    }
    int b = bx - 1563;
    const float* W;
    _Float16* Wt;
    int K, N, Kpad, tid;
    if (b < 256)      { W = W1; Wt = w1t; K = 100; N = 512; Kpad = 128; tid = b * 256 + t; }
    else if (b < 768) { W = W2; Wt = w2t; K = 512; N = 256; Kpad = 512; tid = (b - 256) * 256 + t; }
    else if (b < 896) { W = W3; Wt = w3t; K = 256; N = 128; Kpad = 256; tid = (b - 768) * 256 + t; }
    else              { W = W4; Wt = w4t; K = 128; N = 200; Kpad = 128; tid = (b - 896) * 256 + t; }
    int n = tid / Kpad, k = tid - n * Kpad;
    float v = (k < K && n < N) ? W[(size_t)k * N + n] : 0.f;
    Wt[tid] = (_Float16)v;
}

// aggregation: fp8 gathers, fp32 accumulate. D/16 lanes per node (16 feat/lane).
// OUT8=1: write fp8; OUT8=0: write f16. BR=1: bias+relu epilogue.
template <int D, int BR, int OUT8>
__global__ __launch_bounds__(256) void agg_kernel(
    const unsigned char* __restrict__ H, const int* __restrict__ off,
    const int2* __restrict__ ep, const float* __restrict__ dinv,
    const float* __restrict__ bias, void* __restrict__ O) {
    constexpr int LPN = D / 16;
    int tid = blockIdx.x * 256 + threadIdx.x;
    int node = tid / LPN;
    int sub = tid % LPN;
    if (node >= NN) return;
    int s = off[node], e = off[node + 1];
    float dc = dinv[node];
    float selfw = dc * dc;
    const int base = sub * 16;
    const unsigned char* __restrict__ Hb = H + base;
    float acc[16], t0[16], t1[16];
    dec16(Hb + (size_t)node * D, t0);
#pragma unroll
    for (int i = 0; i < 16; i++) acc[i] = selfw * t0[i];
    int j = s;
    for (; j + 2 <= e; j += 2) {
        int2 q0 = ep[j];
        int2 q1 = ep[j + 1];
        dec16(Hb + (size_t)q0.x * D, t0);
        dec16(Hb + (size_t)q1.x * D, t1);
        float w0 = __int_as_float(q0.y);
        float w1 = __int_as_float(q1.y);
#pragma unroll
        for (int i = 0; i < 16; i++) acc[i] = fmaf(w0, t0[i], acc[i]);
#pragma unroll
        for (int i = 0; i < 16; i++) acc[i] = fmaf(w1, t1[i], acc[i]);
    }
    if (j < e) {
        int2 q0 = ep[j];
        dec16(Hb + (size_t)q0.x * D, t0);
        float w0 = __int_as_float(q0.y);
#pragma unroll
        for (int i = 0; i < 16; i++) acc[i] = fmaf(w0, t0[i], acc[i]);
    }
    if (BR) {
#pragma unroll
        for (int i = 0; i < 16; i++) acc[i] = fmaxf(acc[i] + bias[base + i], 0.f);
    }
    if (OUT8) {
        *(uint4*)((unsigned char*)O + (size_t)node * D + base) = enc16(acc);
    } else {
        U16x8 o0, o1;
#pragma unroll
        for (int i = 0; i < 8; i++) o0.e[i] = (_Float16)acc[i];
#pragma unroll
        for (int i = 0; i < 8; i++) o1.e[i] = (_Float16)acc[8 + i];
        _Float16* Op = (_Float16*)O + (size_t)node * D + base;
        *(uint4*)Op = o0.u4;
        *(uint4*)(Op + 8) = o1.u4;
    }
}

// MFMA GEMM: C[M,N] = A[M,K] @ B^T, B is [Npad,K] f16.
// 128x128 tile, 256 threads (2x2 waves of 64x64), 16x16x32 f16 MFMA.
// LDS row stride 40 elems (80 B) to break 8-way bank aliasing.
// EPI: 0 = f16 store, 1 = bias+relu f16, 2 = bias+relu+column-mean atomic,
//      3 = fp8 store (no bias).
template <int EPI>
__global__ __launch_bounds__(256) void gemm_kernel(
    const _Float16* __restrict__ A, const _Float16* __restrict__ B,
    const float* __restrict__ bias, void* __restrict__ Cb,
    float* __restrict__ outmean, int M, int K, int N) {
    __shared__ _Float16 Asl[128 * 40];
    __shared__ _Float16 Bsl[128 * 40];
    __shared__ float red[128];
    const int m0 = blockIdx.y * 128;
    const int n0 = blockIdx.x * 128;
    const int t = threadIdx.x;
    const int lane = t & 63, w = t >> 6;
    const int wm = (w >> 1) * 64, wn = (w & 1) * 64;
    const int r16 = lane & 15, quad = lane >> 4;

    floatx4 acc[4][4];
    const floatx4 fz = {0.f, 0.f, 0.f, 0.f};
#pragma unroll
    for (int i = 0; i < 4; i++)
#pragma unroll
        for (int j = 0; j < 4; j++) acc[i][j] = fz;

    for (int kc = 0; kc < K; kc += 32) {
        __syncthreads();
#pragma unroll
        for (int i = 0; i < 2; i++) {
            int seg = t + 256 * i;
            int row = seg >> 2, k8 = (seg & 3) * 8;
            int gm = m0 + row;
            if (gm > M - 1) gm = M - 1;
            *(uint4*)(Asl + row * 40 + k8) = *(const uint4*)(A + (size_t)gm * K + kc + k8);
            int gn = n0 + row;  // B padded to Npad multiple of 128
            *(uint4*)(Bsl + row * 40 + k8) = *(const uint4*)(B + (size_t)gn * K + kc + k8);
        }
        __syncthreads();
        f16x8 af[4], bf[4];
#pragma unroll
        for (int i = 0; i < 4; i++)
            af[i] = *(const f16x8*)(Asl + (wm + i * 16 + r16) * 40 + quad * 8);
#pragma unroll
        for (int j = 0; j < 4; j++)
            bf[j] = *(const f16x8*)(Bsl + (wn + j * 16 + r16) * 40 + quad * 8);
#pragma unroll
        for (int i = 0; i < 4; i++)
#pragma unroll
            for (int j = 0; j < 4; j++)
                acc[i][j] = __builtin_amdgcn_mfma_f32_16x16x32_f16(af[i], bf[j], acc[i][j], 0, 0, 0);
    }

    if (EPI == 2) {
        if (t < 128) red[t] = 0.f;
        __syncthreads();
#pragma unroll
        for (int j = 0; j < 4; j++) {
            int col = n0 + wn + j * 16 + r16;
            float s = 0.f;
            if (col < N) {
                float bv = bias[col];
#pragma unroll
                for (int i = 0; i < 4; i++)
#pragma unroll
                    for (int r = 0; r < 4; r++) {
                        int m = m0 + wm + i * 16 + quad * 4 + r;
                        if (m < M) s += fmaxf(acc[i][j][r] + bv, 0.f);
                    }
            }
            atomicAdd(&red[wn + j * 16 + r16], s);
        }
        __syncthreads();
        if (t < 128) {
            int col = n0 + t;
            if (col < N) atomicAdd(outmean + col, red[t] * (1.0f / (float)NN));
        }
    } else {
#pragma unroll
        for (int i = 0; i < 4; i++)
#pragma unroll
            for (int r = 0; r < 4; r++) {
                int m = m0 + wm + i * 16 + quad * 4 + r;
                if (m >= M) continue;
#pragma unroll
                for (int j = 0; j < 4; j++) {
                    int col = n0 + wn + j * 16 + r16;
                    float v = acc[i][j][r];
                    if (EPI == 1) v = fmaxf(v + bias[col], 0.f);
                    if (EPI == 3) {
                        unsigned pk = __builtin_amdgcn_cvt_pk_fp8_f32(v, v, 0, false);
                        ((unsigned char*)Cb)[(size_t)m * N + col] = (unsigned char)(pk & 0xffu);
                    } else {
                        ((_Float16*)Cb)[(size_t)m * N + col] = (_Float16)v;
                    }
                }
            }
    }
}

extern "C" void kernel_launch(void* const* d_in, const int* in_sizes, int n_in,
                              void* d_out, int out_size, void* d_ws, size_t ws_size,
                              hipStream_t stream) {
    const float* x  = (const float*)d_in[0];
    const void*  ei = d_in[1];
    const float* W1 = (const float*)d_in[2];
    const float* b1 = (const float*)d_in[3];
    const float* W2 = (const float*)d_in[4];
    const float* b2 = (const float*)d_in[5];
    const float* W3 = (const float*)d_in[6];
    const float* b3 = (const float*)d_in[7];
    const float* W4 = (const float*)d_in[8];
    const float* b4 = (const float*)d_in[9];
    float* out = (float*)d_out;

    char* ws = (char*)d_ws;
    size_t o = 0;
    auto alloc = [&](size_t bytes) -> void* {
        void* p = ws + o;
        o += (bytes + 255) & ~(size_t)255;
        return p;
    };
    int*      flag  = (int*)alloc(4);
    unsigned* cnt   = (unsigned*)alloc((size_t)NN * 4);
    int*      off   = (int*)alloc((size_t)(NN + 1) * 4);
    unsigned* fillc = (unsigned*)alloc((size_t)NN * 4);
    float*    dinv  = (float*)alloc((size_t)NN * 4);
    int2*     ep    = (int2*)alloc((size_t)NE * 8);
    _Float16* w1t = (_Float16*)alloc((size_t)512 * 128 * 2);
    _Float16* w2t = (_Float16*)alloc((size_t)256 * 512 * 2);
    _Float16* w3t = (_Float16*)alloc((size_t)128 * 256 * 2);
    _Float16* w4t = (_Float16*)alloc((size_t)256 * 128 * 2);
    int*      bsum  = (int*)alloc(256);
    // activation buffers (fp8 for gathered tensors, f16 for GEMM inputs)
    unsigned char* xb  = (unsigned char*)alloc((size_t)NN * 128);      // fp8
    _Float16*      A1b = (_Float16*)alloc((size_t)NN * 128 * 2);
    _Float16*      H1b = (_Float16*)alloc((size_t)NN * 512 * 2);
    unsigned char* t2b = (unsigned char*)alloc((size_t)NN * 256);      // fp8
    _Float16*      H2b = (_Float16*)alloc((size_t)NN * 256 * 2);
    unsigned char* t3b = (unsigned char*)alloc((size_t)NN * 128);      // fp8
    unsigned char* h3b = (unsigned char*)alloc((size_t)NN * 128);      // fp8
    _Float16*      A4b = (_Float16*)alloc((size_t)NN * 128 * 2);

    const int EB = (NE + 255) / 256;     // 3125
    const int NB1 = (NN + 1023) / 1024;  // 49
    const int ZB = (NN + 255) / 256;     // 196

    zero_detect_kernel<<<ZB, 256, 0, stream>>>((const unsigned*)ei, flag, cnt, fillc, out);
    count_kernel<<<EB, 256, 0, stream>>>(ei, flag, cnt);
    scan1_kernel<<<NB1, 256, 0, stream>>>(cnt, off, bsum, dinv);
    scan2_kernel<<<1, 64, 0, stream>>>(bsum, NB1);
    scan3_kernel<<<NB1, 256, 0, stream>>>(off, bsum);
    fill_kernel<<<EB, 256, 0, stream>>>(ei, flag, off, fillc, dinv, ep);
    xwcast_kernel<<<1563 + 1024, 256, 0, stream>>>(x, xb, W1, W2, W3, W4, w1t, w2t, w3t, w4t);

    const int MB = (NN + 127) / 128;   // 391
    const int AB128 = (NN * 8 + 255) / 256;    // 1563 (D=128: 8 lanes/node)
    const int AB256 = (NN * 16 + 255) / 256;   // 3125 (D=256: 16 lanes/node)

    // L1: agg(xb fp8) -> A1 f16; gemm + bias + relu -> H1 [NN,512] f16
    agg_kernel<128, 0, 0><<<AB128, 256, 0, stream>>>(xb, off, ep, dinv, nullptr, A1b);
    gemm_kernel<1><<<dim3(4, MB), 256, 0, stream>>>(A1b, w1t, b1, H1b, nullptr, NN, 128, 512);
    // L2: gemm H1 -> t2 fp8 [NN,256]; agg + bias + relu -> H2 f16
    gemm_kernel<3><<<dim3(2, MB), 256, 0, stream>>>(H1b, w2t, nullptr, t2b, nullptr, NN, 512, 256);
    agg_kernel<256, 1, 0><<<AB256, 256, 0, stream>>>(t2b, off, ep, dinv, b2, H2b);
    // L3: gemm H2 -> t3 fp8 [NN,128]; agg + bias + relu -> h3 fp8
    gemm_kernel<3><<<dim3(1, MB), 256, 0, stream>>>(H2b, w3t, nullptr, t3b, nullptr, NN, 256, 128);
    agg_kernel<128, 1, 1><<<AB128, 256, 0, stream>>>(t3b, off, ep, dinv, b3, h3b);
    // L4: agg(h3 fp8) -> A4 f16; gemm + bias + relu + fused column mean -> out
    agg_kernel<128, 0, 0><<<AB128, 256, 0, stream>>>(h3b, off, ep, dinv, nullptr, A4b);
    gemm_kernel<2><<<dim3(2, MB), 256, 0, stream>>>(A4b, w4t, b4, nullptr, out, NN, 128, 200);
}